// Round 1
// baseline (2754.168 us; speedup 1.0000x reference)
//
#include <hip/hip_runtime.h>
#include <hip/hip_bf16.h>

typedef __attribute__((ext_vector_type(8))) short short8;
typedef __attribute__((ext_vector_type(4))) short short4v;
typedef __attribute__((ext_vector_type(4))) float f32x4;

#define TM 64          // nodes per block (mlp)
#define SX 136         // lds row stride (bf16) for X / H2 chunk (128 + 8 pad)
#define S1 264         // lds row stride for H1              (256 + 8 pad)

#define BK_LG 6        // 64 nodes per aggregation bucket
#define BK_N  64
#define MAX_NB 4096    // bucket-count cap (LDS histogram size)
#define PS_CHUNK 16384 // edges per bscatter block

__device__ __forceinline__ short f2bf(float x) {
    union { float f; unsigned u; } v; v.f = x;
    unsigned r = v.u + 0x7fffu + ((v.u >> 16) & 1u);
    return (short)(r >> 16);
}

// ---- weight prep: f32 [k][n] -> bf16 transposed [n][k] ----
__global__ __launch_bounds__(256) void prep_weights(
        const float* __restrict__ W1, const float* __restrict__ W2,
        const float* __restrict__ W3,
        short* __restrict__ W1t, short* __restrict__ W2t, short* __restrict__ W3t) {
    int i = blockIdx.x * 256 + threadIdx.x;
    if (i < 32768) {                       // W1: 128x256 -> W1t: 256x128
        int n = i >> 7, k = i & 127;
        W1t[i] = f2bf(W1[k * 256 + n]);
    } else if (i < 32768 + 131072) {       // W2: 256x512 -> W2t: 512x256
        int j = i - 32768;
        int n = j >> 8, k = j & 255;
        W2t[j] = f2bf(W2[k * 512 + n]);
    } else if (i < 229376) {               // W3: 512x128 -> W3t: 128x512
        int j = i - 163840;
        int n = j >> 9, k = j & 511;
        W3t[j] = f2bf(W3[k * 128 + n]);
    }
}

// ---- fused 3-layer MLP, bf16 MFMA, 64 nodes/block, 4 waves by out-col ----
__global__ __launch_bounds__(256) void mlp_kernel(
        const float* __restrict__ X,
        const float* __restrict__ b1f, const float* __restrict__ b2f,
        const float* __restrict__ b3f,
        const short* __restrict__ W1t, const short* __restrict__ W2t,
        const short* __restrict__ W3t,
        float* __restrict__ out, int n_nodes) {
    __shared__ short lds[TM * S1 + TM * SX];   // H1 (33792B) + X/H2chunk (17408B)
    short* ldsH1 = lds;
    short* ldsX  = lds + TM * S1;   // X aliases H2 chunk (X dead after layer1)
    short* ldsH2 = ldsX;

    const int tid  = threadIdx.x;
    const int ch   = tid >> 6;      // wave = output-column group
    const int lane = tid & 63;
    const int ln   = lane & 15;
    const int quad = lane >> 4;
    const long node0 = (long)blockIdx.x * TM;

    // ---- stage X -> LDS (f32 -> bf16): 64 rows x 32 float4 ----
    for (int i = tid; i < TM * 32; i += 256) {
        int r = i >> 5, c4 = i & 31;
        long node = node0 + r;
        float4 v = make_float4(0.f, 0.f, 0.f, 0.f);
        if (node < n_nodes) v = *(const float4*)&X[node * 128 + c4 * 4];
        short4v s;
        s.x = f2bf(v.x); s.y = f2bf(v.y); s.z = f2bf(v.z); s.w = f2bf(v.w);
        *(short4v*)&ldsX[r * SX + c4 * 4] = s;
    }
    __syncthreads();

    // ---- layer 1: H1[64x256] = relu(X @ W1 + b1); wave cols ch*64..+64 ----
#pragma unroll
    for (int nt = 0; nt < 4; ++nt) {
        int n = ch * 64 + nt * 16 + ln;
        const short* bp = &W1t[n * 128 + quad * 8];
        short8 b[4];
#pragma unroll
        for (int kk = 0; kk < 4; ++kk) b[kk] = *(const short8*)(bp + kk * 32);
        float bias = b1f[n];
#pragma unroll
        for (int m = 0; m < 4; ++m) {
            f32x4 c = {0.f, 0.f, 0.f, 0.f};
#pragma unroll
            for (int kk = 0; kk < 4; ++kk) {
                short8 a = *(const short8*)&ldsX[(m * 16 + ln) * SX + kk * 32 + quad * 8];
                c = __builtin_amdgcn_mfma_f32_16x16x32_bf16(a, b[kk], c, 0, 0, 0);
            }
#pragma unroll
            for (int rr = 0; rr < 4; ++rr) {
                float h = c[rr] + bias;
                h = h > 0.f ? h : 0.f;
                ldsH1[(m * 16 + quad * 4 + rr) * S1 + n] = f2bf(h);
            }
        }
    }
    __syncthreads();   // H1 complete; X region now free for H2 chunks

    // ---- layers 2+3 fused over 4 chunks of 128 H2 cols ----
    f32x4 acc3[4][2] = {};
#pragma unroll 1
    for (int cc = 0; cc < 4; ++cc) {
        // layer 2 part: H2[:, cc*128..+128] = relu(H1 @ W2[:,chunk] + b2)
#pragma unroll
        for (int nt = 0; nt < 2; ++nt) {
            int n2 = cc * 128 + ch * 32 + nt * 16 + ln;
            const short* bp = &W2t[n2 * 256 + quad * 8];
            short8 b[8];
#pragma unroll
            for (int kk = 0; kk < 8; ++kk) b[kk] = *(const short8*)(bp + kk * 32);
            float bias = b2f[n2];
            int nl = ch * 32 + nt * 16 + ln;   // col within chunk
#pragma unroll
            for (int m = 0; m < 4; ++m) {
                f32x4 c = {0.f, 0.f, 0.f, 0.f};
#pragma unroll
                for (int kk = 0; kk < 8; ++kk) {
                    short8 a = *(const short8*)&ldsH1[(m * 16 + ln) * S1 + kk * 32 + quad * 8];
                    c = __builtin_amdgcn_mfma_f32_16x16x32_bf16(a, b[kk], c, 0, 0, 0);
                }
#pragma unroll
                for (int rr = 0; rr < 4; ++rr) {
                    float h = c[rr] + bias;
                    h = h > 0.f ? h : 0.f;
                    ldsH2[(m * 16 + quad * 4 + rr) * SX + nl] = f2bf(h);
                }
            }
        }
        __syncthreads();   // chunk fully written

        // layer 3 part: acc3 += H2chunk @ W3[chunk rows, :]
#pragma unroll
        for (int nt = 0; nt < 2; ++nt) {
            int n3 = ch * 32 + nt * 16 + ln;
            const short* bp = &W3t[n3 * 512 + cc * 128 + quad * 8];
            short8 b[4];
#pragma unroll
            for (int kk = 0; kk < 4; ++kk) b[kk] = *(const short8*)(bp + kk * 32);
#pragma unroll
            for (int m = 0; m < 4; ++m) {
#pragma unroll
                for (int kk = 0; kk < 4; ++kk) {
                    short8 a = *(const short8*)&ldsH2[(m * 16 + ln) * SX + kk * 32 + quad * 8];
                    acc3[m][nt] = __builtin_amdgcn_mfma_f32_16x16x32_bf16(a, b[kk], acc3[m][nt], 0, 0, 0);
                }
            }
        }
        __syncthreads();   // chunk consumed; safe to overwrite next iter
    }

    // ---- epilogue: out[node][n3] = acc3 + b3 ----
#pragma unroll
    for (int nt = 0; nt < 2; ++nt) {
        int n3 = ch * 32 + nt * 16 + ln;
        float bias = b3f[n3];
#pragma unroll
        for (int m = 0; m < 4; ++m) {
#pragma unroll
            for (int rr = 0; rr < 4; ++rr) {
                long node = node0 + m * 16 + quad * 4 + rr;
                if (node < n_nodes) out[node * 256 + n3] = acc3[m][nt][rr] + bias;
            }
        }
    }
}

// ============ bucketed aggregation (replaces full CSR sort) ============
// Buckets of 64 consecutive dst nodes. Edges are packed (dstloc<<26)|src.

// ---- B1: bucket histogram with per-block LDS aggregation ----
__global__ __launch_bounds__(256) void bhist_kernel(
        const int* __restrict__ dst, int* __restrict__ bcnt,
        int n_edges, int nb) {
    __shared__ int h[MAX_NB];
    int tid = threadIdx.x;
    for (int b = tid; b < nb; b += 256) h[b] = 0;
    __syncthreads();
    for (int e = blockIdx.x * 256 + tid; e < n_edges; e += gridDim.x * 256)
        atomicAdd(&h[dst[e] >> BK_LG], 1);
    __syncthreads();
    for (int b = tid; b < nb; b += 256) {
        int c = h[b];
        if (c) atomicAdd(&bcnt[b], c);
    }
}

// ---- B2: single-block exclusive scan of bucket counts (nb <= MAX_NB) ----
__global__ __launch_bounds__(256) void bscan_kernel(
        const int* __restrict__ bcnt, int* __restrict__ boffs,
        int* __restrict__ bcur, int nb) {
    __shared__ int s[256];
    int t = threadIdx.x;
    int per = (nb + 255) >> 8;
    int lo = t * per;
    int sum = 0;
    for (int i = 0; i < per; ++i) {
        int b = lo + i;
        if (b < nb) sum += bcnt[b];
    }
    s[t] = sum;
    __syncthreads();
#pragma unroll
    for (int off = 1; off < 256; off <<= 1) {
        int v = (t >= off) ? s[t - off] : 0;
        __syncthreads();
        s[t] += v;
        __syncthreads();
    }
    int base = (t == 0) ? 0 : s[t - 1];
    for (int i = 0; i < per; ++i) {
        int b = lo + i;
        if (b < nb) {
            int c = bcnt[b];
            boffs[b] = base;
            bcur[b]  = base;
            base += c;
        }
    }
    if (t == 255) boffs[nb] = s[255];
}

// ---- B3: scatter packed edges into bucket regions ----
// Per-block LDS histogram + bulk cursor reservation -> each block writes a
// contiguous run per bucket (avg ~10 edges = 42B) instead of isolated 4B.
__global__ __launch_bounds__(256) void bscatter_kernel(
        const int* __restrict__ src, const int* __restrict__ dst,
        int* __restrict__ bcur, unsigned* __restrict__ pairs,
        int n_edges, int nb) {
    __shared__ int h[MAX_NB];
    int tid = threadIdx.x;
    long e0 = (long)blockIdx.x * PS_CHUNK;
    int cnt = n_edges - (int)e0;
    if (cnt > PS_CHUNK) cnt = PS_CHUNK;
    if (cnt <= 0) return;
    for (int b = tid; b < nb; b += 256) h[b] = 0;
    __syncthreads();
    for (int i = tid; i < cnt; i += 256)
        atomicAdd(&h[dst[e0 + i] >> BK_LG], 1);
    __syncthreads();
    for (int b = tid; b < nb; b += 256) {
        int c = h[b];
        h[b] = c ? atomicAdd(&bcur[b], c) : 0;
    }
    __syncthreads();
    for (int i = tid; i < cnt; i += 256) {
        int d = dst[e0 + i];
        int s = src[e0 + i];
        int p = atomicAdd(&h[d >> BK_LG], 1);
        pairs[p] = ((unsigned)(d & (BK_N - 1)) << 26) | (unsigned)s;
    }
}

// ---- B4: block-per-bucket aggregation in LDS ----
// 64-node x 128-col f32 accumulator (32KB) -> 4-5 blocks/CU, 16+ waves.
// 128 threads gather a full 512B h[src] row coalesced; ds_add_f32 into LDS
// (no-return, 2-way bank aliasing = free); one coalesced writeback.
__global__ __launch_bounds__(256) void bagg_kernel(
        const unsigned* __restrict__ pairs, const int* __restrict__ boffs,
        float* __restrict__ out, int n_nodes) {
    __shared__ float acc[BK_N * 128];
    __shared__ unsigned eb[512];
    const int tid  = threadIdx.x;
    const int col  = tid & 127;
    const int half = tid >> 7;       // which of 2 concurrent edges
    const int node0 = blockIdx.x << BK_LG;

    for (int i = tid; i < BK_N * 128; i += 256) acc[i] = 0.f;

    const int s0 = boffs[blockIdx.x];
    const int s1 = boffs[blockIdx.x + 1];

    for (int j0 = s0; j0 < s1; j0 += 512) {
        int m = s1 - j0;
        if (m > 512) m = 512;
        for (int i = tid; i < m; i += 256) eb[i] = pairs[j0 + i];
        __syncthreads();
        int i = half;
        for (; i + 8 <= m; i += 8) {
            unsigned p0 = eb[i], p1 = eb[i + 2], p2 = eb[i + 4], p3 = eb[i + 6];
            float v0 = out[(long)(p0 & 0x03FFFFFFu) * 256 + col];
            float v1 = out[(long)(p1 & 0x03FFFFFFu) * 256 + col];
            float v2 = out[(long)(p2 & 0x03FFFFFFu) * 256 + col];
            float v3 = out[(long)(p3 & 0x03FFFFFFu) * 256 + col];
            atomicAdd(&acc[(p0 >> 26) * 128 + col], v0);
            atomicAdd(&acc[(p1 >> 26) * 128 + col], v1);
            atomicAdd(&acc[(p2 >> 26) * 128 + col], v2);
            atomicAdd(&acc[(p3 >> 26) * 128 + col], v3);
        }
        for (; i < m; i += 2) {
            unsigned pk = eb[i];
            float v = out[(long)(pk & 0x03FFFFFFu) * 256 + col];
            atomicAdd(&acc[(pk >> 26) * 128 + col], v);
        }
        __syncthreads();   // all atomics done; eb safe to overwrite
    }

    for (int i = tid; i < BK_N * 128; i += 256) {
        int n = node0 + (i >> 7);
        if (n < n_nodes) out[(long)n * 256 + 128 + (i & 127)] = acc[i];
    }
}

// ---- fallback path (small ws): zero agg + atomic scatter-add ----
__global__ __launch_bounds__(256) void zero_agg(float* __restrict__ out, int n_nodes) {
    int i = blockIdx.x * 256 + threadIdx.x;
    int total = n_nodes * 32;
    for (; i < total; i += gridDim.x * 256) {
        int n = i >> 5, q = i & 31;
        *(float4*)&out[(long)n * 256 + 128 + q * 4] = make_float4(0.f, 0.f, 0.f, 0.f);
    }
}

__global__ __launch_bounds__(256) void edge_agg(
        const int* __restrict__ src, const int* __restrict__ dst,
        float* __restrict__ out, int n_edges) {
    int e = blockIdx.x * 8 + (threadIdx.x >> 5);
    if (e >= n_edges) return;
    int l = threadIdx.x & 31;
    long s = src[e];
    long d = dst[e];
    const float4 v = *(const float4*)&out[s * 256 + l * 4];
    float* p = &out[d * 256 + 128 + l * 4];
    unsafeAtomicAdd(p + 0, v.x);
    unsafeAtomicAdd(p + 1, v.y);
    unsafeAtomicAdd(p + 2, v.z);
    unsafeAtomicAdd(p + 3, v.w);
}

extern "C" void kernel_launch(void* const* d_in, const int* in_sizes, int n_in,
                              void* d_out, int out_size, void* d_ws, size_t ws_size,
                              hipStream_t stream) {
    const float* X   = (const float*)d_in[0];
    const int*   src = (const int*)d_in[1];
    const int*   dst = (const int*)d_in[2];
    const float* W1  = (const float*)d_in[3];
    const float* b1  = (const float*)d_in[4];
    const float* W2  = (const float*)d_in[5];
    const float* b2  = (const float*)d_in[6];
    const float* W3  = (const float*)d_in[7];
    const float* b3  = (const float*)d_in[8];
    float* out = (float*)d_out;

    const int n_nodes = in_sizes[0] / 128;
    const int n_edges = in_sizes[1];
    const int nb = (n_nodes + BK_N - 1) >> BK_LG;

    char* ws = (char*)d_ws;
    short* W1t = (short*)ws;              // 32768 bf16
    short* W2t = W1t + 32768;             // 131072 bf16
    short* W3t = W2t + 131072;            // 65536 bf16  (total 448 KiB used)

    int* bcnt   = (int*)(ws + 512 * 1024);        // nb
    int* boffs  = bcnt + nb;                      // nb + 1
    int* bcur   = boffs + nb + 1;                 // nb
    unsigned* pairs = (unsigned*)(bcur + nb);     // n_edges packed edges

    size_t need = 512 * 1024 +
                  sizeof(int) * ((size_t)3 * nb + 1 + (size_t)n_edges);
    const bool use_bucket = (ws_size >= need) && (nb <= MAX_NB) &&
                            (n_nodes < (1 << 26));

    prep_weights<<<896, 256, 0, stream>>>(W1, W2, W3, W1t, W2t, W3t);
    mlp_kernel<<<(n_nodes + TM - 1) / TM, 256, 0, stream>>>(
        X, b1, b2, b3, W1t, W2t, W3t, out, n_nodes);

    if (use_bucket) {
        hipMemsetAsync(bcnt, 0, (size_t)nb * 4, stream);
        bhist_kernel<<<256, 256, 0, stream>>>(dst, bcnt, n_edges, nb);
        bscan_kernel<<<1, 256, 0, stream>>>(bcnt, boffs, bcur, nb);
        bscatter_kernel<<<(n_edges + PS_CHUNK - 1) / PS_CHUNK, 256, 0, stream>>>(
            src, dst, bcur, pairs, n_edges, nb);
        bagg_kernel<<<nb, 256, 0, stream>>>(pairs, boffs, out, n_nodes);
    } else {
        zero_agg<<<3125, 256, 0, stream>>>(out, n_nodes);
        edge_agg<<<(n_edges + 7) / 8, 256, 0, stream>>>(src, dst, out, n_edges);
    }
}

// Round 2
// 617.253 us; speedup vs baseline: 4.4620x; 4.4620x over previous
//
#include <hip/hip_runtime.h>
#include <hip/hip_bf16.h>

typedef __attribute__((ext_vector_type(8))) short short8;
typedef __attribute__((ext_vector_type(4))) short short4v;
typedef __attribute__((ext_vector_type(4))) float f32x4;

#define TM 64          // nodes per block (mlp)
#define SX 136         // lds row stride (bf16) for X / H2 chunk (128 + 8 pad)
#define S1 264         // lds row stride for H1              (256 + 8 pad)

#define BK_LG 6        // 64 nodes per aggregation bucket
#define BK_N  64
#define MAX_NB 4096    // bucket-count cap (LDS histogram size)
#define PS_CHUNK 16384 // edges per bscatter block

__device__ __forceinline__ short f2bf(float x) {
    union { float f; unsigned u; } v; v.f = x;
    unsigned r = v.u + 0x7fffu + ((v.u >> 16) & 1u);
    return (short)(r >> 16);
}

// ---- weight prep: f32 [k][n] -> bf16 transposed [n][k] ----
__global__ __launch_bounds__(256) void prep_weights(
        const float* __restrict__ W1, const float* __restrict__ W2,
        const float* __restrict__ W3,
        short* __restrict__ W1t, short* __restrict__ W2t, short* __restrict__ W3t) {
    int i = blockIdx.x * 256 + threadIdx.x;
    if (i < 32768) {                       // W1: 128x256 -> W1t: 256x128
        int n = i >> 7, k = i & 127;
        W1t[i] = f2bf(W1[k * 256 + n]);
    } else if (i < 32768 + 131072) {       // W2: 256x512 -> W2t: 512x256
        int j = i - 32768;
        int n = j >> 8, k = j & 255;
        W2t[j] = f2bf(W2[k * 512 + n]);
    } else if (i < 229376) {               // W3: 512x128 -> W3t: 128x512
        int j = i - 163840;
        int n = j >> 9, k = j & 511;
        W3t[j] = f2bf(W3[k * 128 + n]);
    }
}

// ---- fused 3-layer MLP, bf16 MFMA, 64 nodes/block, 4 waves by out-col ----
__global__ __launch_bounds__(256) void mlp_kernel(
        const float* __restrict__ X,
        const float* __restrict__ b1f, const float* __restrict__ b2f,
        const float* __restrict__ b3f,
        const short* __restrict__ W1t, const short* __restrict__ W2t,
        const short* __restrict__ W3t,
        float* __restrict__ out, int n_nodes) {
    __shared__ short lds[TM * S1 + TM * SX];   // H1 (33792B) + X/H2chunk (17408B)
    short* ldsH1 = lds;
    short* ldsX  = lds + TM * S1;   // X aliases H2 chunk (X dead after layer1)
    short* ldsH2 = ldsX;

    const int tid  = threadIdx.x;
    const int ch   = tid >> 6;      // wave = output-column group
    const int lane = tid & 63;
    const int ln   = lane & 15;
    const int quad = lane >> 4;
    const long node0 = (long)blockIdx.x * TM;

    // ---- stage X -> LDS (f32 -> bf16): 64 rows x 32 float4 ----
    for (int i = tid; i < TM * 32; i += 256) {
        int r = i >> 5, c4 = i & 31;
        long node = node0 + r;
        float4 v = make_float4(0.f, 0.f, 0.f, 0.f);
        if (node < n_nodes) v = *(const float4*)&X[node * 128 + c4 * 4];
        short4v s;
        s.x = f2bf(v.x); s.y = f2bf(v.y); s.z = f2bf(v.z); s.w = f2bf(v.w);
        *(short4v*)&ldsX[r * SX + c4 * 4] = s;
    }
    __syncthreads();

    // ---- layer 1: H1[64x256] = relu(X @ W1 + b1); wave cols ch*64..+64 ----
#pragma unroll
    for (int nt = 0; nt < 4; ++nt) {
        int n = ch * 64 + nt * 16 + ln;
        const short* bp = &W1t[n * 128 + quad * 8];
        short8 b[4];
#pragma unroll
        for (int kk = 0; kk < 4; ++kk) b[kk] = *(const short8*)(bp + kk * 32);
        float bias = b1f[n];
#pragma unroll
        for (int m = 0; m < 4; ++m) {
            f32x4 c = {0.f, 0.f, 0.f, 0.f};
#pragma unroll
            for (int kk = 0; kk < 4; ++kk) {
                short8 a = *(const short8*)&ldsX[(m * 16 + ln) * SX + kk * 32 + quad * 8];
                c = __builtin_amdgcn_mfma_f32_16x16x32_bf16(a, b[kk], c, 0, 0, 0);
            }
#pragma unroll
            for (int rr = 0; rr < 4; ++rr) {
                float h = c[rr] + bias;
                h = h > 0.f ? h : 0.f;
                ldsH1[(m * 16 + quad * 4 + rr) * S1 + n] = f2bf(h);
            }
        }
    }
    __syncthreads();   // H1 complete; X region now free for H2 chunks

    // ---- layers 2+3 fused over 4 chunks of 128 H2 cols ----
    f32x4 acc3[4][2] = {};
#pragma unroll 1
    for (int cc = 0; cc < 4; ++cc) {
        // layer 2 part: H2[:, cc*128..+128] = relu(H1 @ W2[:,chunk] + b2)
#pragma unroll
        for (int nt = 0; nt < 2; ++nt) {
            int n2 = cc * 128 + ch * 32 + nt * 16 + ln;
            const short* bp = &W2t[n2 * 256 + quad * 8];
            short8 b[8];
#pragma unroll
            for (int kk = 0; kk < 8; ++kk) b[kk] = *(const short8*)(bp + kk * 32);
            float bias = b2f[n2];
            int nl = ch * 32 + nt * 16 + ln;   // col within chunk
#pragma unroll
            for (int m = 0; m < 4; ++m) {
                f32x4 c = {0.f, 0.f, 0.f, 0.f};
#pragma unroll
                for (int kk = 0; kk < 8; ++kk) {
                    short8 a = *(const short8*)&ldsH1[(m * 16 + ln) * S1 + kk * 32 + quad * 8];
                    c = __builtin_amdgcn_mfma_f32_16x16x32_bf16(a, b[kk], c, 0, 0, 0);
                }
#pragma unroll
                for (int rr = 0; rr < 4; ++rr) {
                    float h = c[rr] + bias;
                    h = h > 0.f ? h : 0.f;
                    ldsH2[(m * 16 + quad * 4 + rr) * SX + nl] = f2bf(h);
                }
            }
        }
        __syncthreads();   // chunk fully written

        // layer 3 part: acc3 += H2chunk @ W3[chunk rows, :]
#pragma unroll
        for (int nt = 0; nt < 2; ++nt) {
            int n3 = ch * 32 + nt * 16 + ln;
            const short* bp = &W3t[n3 * 512 + cc * 128 + quad * 8];
            short8 b[4];
#pragma unroll
            for (int kk = 0; kk < 4; ++kk) b[kk] = *(const short8*)(bp + kk * 32);
#pragma unroll
            for (int m = 0; m < 4; ++m) {
#pragma unroll
                for (int kk = 0; kk < 4; ++kk) {
                    short8 a = *(const short8*)&ldsH2[(m * 16 + ln) * SX + kk * 32 + quad * 8];
                    acc3[m][nt] = __builtin_amdgcn_mfma_f32_16x16x32_bf16(a, b[kk], acc3[m][nt], 0, 0, 0);
                }
            }
        }
        __syncthreads();   // chunk consumed; safe to overwrite next iter
    }

    // ---- epilogue: out[node][n3] = acc3 + b3 ----
#pragma unroll
    for (int nt = 0; nt < 2; ++nt) {
        int n3 = ch * 32 + nt * 16 + ln;
        float bias = b3f[n3];
#pragma unroll
        for (int m = 0; m < 4; ++m) {
#pragma unroll
            for (int rr = 0; rr < 4; ++rr) {
                long node = node0 + m * 16 + quad * 4 + rr;
                if (node < n_nodes) out[node * 256 + n3] = acc3[m][nt][rr] + bias;
            }
        }
    }
}

// ============ two-level CSR build: bucket scatter + in-bucket sort ============
// Buckets of 64 consecutive dst nodes. Edges packed (dstloc<<26)|src.

// ---- B1: bucket histogram with per-block LDS aggregation ----
__global__ __launch_bounds__(256) void bhist_kernel(
        const int* __restrict__ dst, int* __restrict__ bcnt,
        int n_edges, int nb) {
    __shared__ int h[MAX_NB];
    int tid = threadIdx.x;
    for (int b = tid; b < nb; b += 256) h[b] = 0;
    __syncthreads();
    for (int e = blockIdx.x * 256 + tid; e < n_edges; e += gridDim.x * 256)
        atomicAdd(&h[dst[e] >> BK_LG], 1);
    __syncthreads();
    for (int b = tid; b < nb; b += 256) {
        int c = h[b];
        if (c) atomicAdd(&bcnt[b], c);
    }
}

// ---- B2: single-block exclusive scan of bucket counts (nb <= MAX_NB) ----
__global__ __launch_bounds__(256) void bscan_kernel(
        const int* __restrict__ bcnt, int* __restrict__ boffs,
        int* __restrict__ bcur, int nb) {
    __shared__ int s[256];
    int t = threadIdx.x;
    int per = (nb + 255) >> 8;
    int lo = t * per;
    int sum = 0;
    for (int i = 0; i < per; ++i) {
        int b = lo + i;
        if (b < nb) sum += bcnt[b];
    }
    s[t] = sum;
    __syncthreads();
#pragma unroll
    for (int off = 1; off < 256; off <<= 1) {
        int v = (t >= off) ? s[t - off] : 0;
        __syncthreads();
        s[t] += v;
        __syncthreads();
    }
    int base = (t == 0) ? 0 : s[t - 1];
    for (int i = 0; i < per; ++i) {
        int b = lo + i;
        if (b < nb) {
            int c = bcnt[b];
            boffs[b] = base;
            bcur[b]  = base;
            base += c;
        }
    }
    if (t == 255) boffs[nb] = s[255];
}

// ---- B3: scatter packed edges into bucket regions ----
// Per-block LDS histogram + bulk cursor reservation -> each block writes a
// contiguous run per bucket (avg ~10 edges = 42B) instead of isolated 4B.
__global__ __launch_bounds__(256) void bscatter_kernel(
        const int* __restrict__ src, const int* __restrict__ dst,
        int* __restrict__ bcur, unsigned* __restrict__ pairs,
        int n_edges, int nb) {
    __shared__ int h[MAX_NB];
    int tid = threadIdx.x;
    long e0 = (long)blockIdx.x * PS_CHUNK;
    int cnt = n_edges - (int)e0;
    if (cnt > PS_CHUNK) cnt = PS_CHUNK;
    if (cnt <= 0) return;
    for (int b = tid; b < nb; b += 256) h[b] = 0;
    __syncthreads();
    for (int i = tid; i < cnt; i += 256)
        atomicAdd(&h[dst[e0 + i] >> BK_LG], 1);
    __syncthreads();
    for (int b = tid; b < nb; b += 256) {
        int c = h[b];
        h[b] = c ? atomicAdd(&bcur[b], c) : 0;
    }
    __syncthreads();
    for (int i = tid; i < cnt; i += 256) {
        int d = dst[e0 + i];
        int s = src[e0 + i];
        int p = atomicAdd(&h[d >> BK_LG], 1);
        pairs[p] = ((unsigned)(d & (BK_N - 1)) << 26) | (unsigned)s;
    }
}

// ---- B4: in-bucket 64-way counting sort -> full per-node CSR ----
// Block per bucket. Pass 1: LDS histogram of dstloc + serial 64-scan ->
// absolute per-node offsets (bucket regions are globally ordered, so
// offs[node] = boffs[b] + local prefix). Pass 2: re-read pairs (L2-hot),
// scatter src into its exact CSR slot. All writes land in the bucket's
// ~8KB window -> L2-resident, flushed once, no partial-line amplification.
__global__ __launch_bounds__(256) void bsort_kernel(
        const unsigned* __restrict__ pairs, const int* __restrict__ boffs,
        int* __restrict__ offs, int* __restrict__ esrc,
        int n_nodes, int n_edges) {
    __shared__ int hist[BK_N];
    __shared__ int cur[BK_N];
    const int tid = threadIdx.x;
    const int b = blockIdx.x;
    const int base = boffs[b];
    const int cnt = boffs[b + 1] - base;

    if (tid < BK_N) hist[tid] = 0;
    __syncthreads();
    for (int i = tid; i < cnt; i += 256)
        atomicAdd(&hist[pairs[base + i] >> 26], 1);
    __syncthreads();
    if (tid == 0) {
        int run = base;
#pragma unroll
        for (int k = 0; k < BK_N; ++k) { cur[k] = run; run += hist[k]; }
    }
    __syncthreads();
    if (tid < BK_N) {
        int node = (b << BK_LG) + tid;
        if (node < n_nodes) offs[node] = cur[tid];
    }
    if (b == 0 && tid == 0) offs[n_nodes] = n_edges;
    __syncthreads();   // offs written before cursors mutate
    for (int i = tid; i < cnt; i += 256) {
        unsigned p = pairs[base + i];
        int pos = atomicAdd(&cur[p >> 26], 1);
        esrc[pos] = (int)(p & 0x03FFFFFFu);
    }
}

// ---- aggregation: one wave per node, no atomics, no shfl (round-0) ----
__global__ __launch_bounds__(256) void agg_kernel(
        const int* __restrict__ esrc, const int* __restrict__ offs,
        float* __restrict__ out, int n_nodes) {
    int node = blockIdx.x * 4 + (threadIdx.x >> 6);
    if (node >= n_nodes) return;
    const int l2 = (threadIdx.x & 63) * 2;
    const int s0 = offs[node];
    const int s1 = offs[node + 1];
    float ax = 0.f, ay = 0.f;
    int j = s0;
    for (; j + 8 <= s1; j += 8) {
        int s[8];
#pragma unroll
        for (int u = 0; u < 8; ++u) s[u] = esrc[j + u];
        float2 v[8];
#pragma unroll
        for (int u = 0; u < 8; ++u) v[u] = *(const float2*)&out[(long)s[u] * 256 + l2];
#pragma unroll
        for (int u = 0; u < 8; ++u) { ax += v[u].x; ay += v[u].y; }
    }
    for (; j < s1; ++j) {
        float2 v = *(const float2*)&out[(long)esrc[j] * 256 + l2];
        ax += v.x; ay += v.y;
    }
    *(float2*)&out[(long)node * 256 + 128 + l2] = make_float2(ax, ay);
}

// ---- mid fallback: block-per-bucket LDS accumulation (round-1, correct
//      for unsorted pairs; used only when ws can't hold esrc+offs) ----
__global__ __launch_bounds__(256) void bagg_kernel(
        const unsigned* __restrict__ pairs, const int* __restrict__ boffs,
        float* __restrict__ out, int n_nodes) {
    __shared__ float acc[BK_N * 128];
    __shared__ unsigned eb[512];
    const int tid  = threadIdx.x;
    const int col  = tid & 127;
    const int half = tid >> 7;
    const int node0 = blockIdx.x << BK_LG;

    for (int i = tid; i < BK_N * 128; i += 256) acc[i] = 0.f;

    const int s0 = boffs[blockIdx.x];
    const int s1 = boffs[blockIdx.x + 1];

    for (int j0 = s0; j0 < s1; j0 += 512) {
        int m = s1 - j0;
        if (m > 512) m = 512;
        for (int i = tid; i < m; i += 256) eb[i] = pairs[j0 + i];
        __syncthreads();
        int i = half;
        for (; i + 8 <= m; i += 8) {
            unsigned p0 = eb[i], p1 = eb[i + 2], p2 = eb[i + 4], p3 = eb[i + 6];
            float v0 = out[(long)(p0 & 0x03FFFFFFu) * 256 + col];
            float v1 = out[(long)(p1 & 0x03FFFFFFu) * 256 + col];
            float v2 = out[(long)(p2 & 0x03FFFFFFu) * 256 + col];
            float v3 = out[(long)(p3 & 0x03FFFFFFu) * 256 + col];
            atomicAdd(&acc[(p0 >> 26) * 128 + col], v0);
            atomicAdd(&acc[(p1 >> 26) * 128 + col], v1);
            atomicAdd(&acc[(p2 >> 26) * 128 + col], v2);
            atomicAdd(&acc[(p3 >> 26) * 128 + col], v3);
        }
        for (; i < m; i += 2) {
            unsigned pk = eb[i];
            float v = out[(long)(pk & 0x03FFFFFFu) * 256 + col];
            atomicAdd(&acc[(pk >> 26) * 128 + col], v);
        }
        __syncthreads();
    }

    for (int i = tid; i < BK_N * 128; i += 256) {
        int n = node0 + (i >> 7);
        if (n < n_nodes) out[(long)n * 256 + 128 + (i & 127)] = acc[i];
    }
}

// ---- last fallback (tiny ws): zero agg + atomic scatter-add ----
__global__ __launch_bounds__(256) void zero_agg(float* __restrict__ out, int n_nodes) {
    int i = blockIdx.x * 256 + threadIdx.x;
    int total = n_nodes * 32;
    for (; i < total; i += gridDim.x * 256) {
        int n = i >> 5, q = i & 31;
        *(float4*)&out[(long)n * 256 + 128 + q * 4] = make_float4(0.f, 0.f, 0.f, 0.f);
    }
}

__global__ __launch_bounds__(256) void edge_agg(
        const int* __restrict__ src, const int* __restrict__ dst,
        float* __restrict__ out, int n_edges) {
    int e = blockIdx.x * 8 + (threadIdx.x >> 5);
    if (e >= n_edges) return;
    int l = threadIdx.x & 31;
    long s = src[e];
    long d = dst[e];
    const float4 v = *(const float4*)&out[s * 256 + l * 4];
    float* p = &out[d * 256 + 128 + l * 4];
    unsafeAtomicAdd(p + 0, v.x);
    unsafeAtomicAdd(p + 1, v.y);
    unsafeAtomicAdd(p + 2, v.z);
    unsafeAtomicAdd(p + 3, v.w);
}

extern "C" void kernel_launch(void* const* d_in, const int* in_sizes, int n_in,
                              void* d_out, int out_size, void* d_ws, size_t ws_size,
                              hipStream_t stream) {
    const float* X   = (const float*)d_in[0];
    const int*   src = (const int*)d_in[1];
    const int*   dst = (const int*)d_in[2];
    const float* W1  = (const float*)d_in[3];
    const float* b1  = (const float*)d_in[4];
    const float* W2  = (const float*)d_in[5];
    const float* b2  = (const float*)d_in[6];
    const float* W3  = (const float*)d_in[7];
    const float* b3  = (const float*)d_in[8];
    float* out = (float*)d_out;

    const int n_nodes = in_sizes[0] / 128;
    const int n_edges = in_sizes[1];
    const int nb = (n_nodes + BK_N - 1) >> BK_LG;

    char* ws = (char*)d_ws;
    short* W1t = (short*)ws;              // 32768 bf16
    short* W2t = W1t + 32768;             // 131072 bf16
    short* W3t = W2t + 131072;            // 65536 bf16  (total 448 KiB used)

    int* bcnt   = (int*)(ws + 512 * 1024);        // nb
    int* boffs  = bcnt + nb;                      // nb + 1
    int* bcur   = boffs + nb + 1;                 // nb
    int* offs   = bcur + nb;                      // n_nodes + 1
    unsigned* pairs = (unsigned*)(offs + n_nodes + 1);  // n_edges
    int* esrc   = (int*)(pairs + n_edges);        // n_edges

    size_t base_need = 512 * 1024 +
                       sizeof(int) * ((size_t)3 * nb + 1 + (size_t)n_nodes + 1);
    size_t need_full = base_need + sizeof(int) * (size_t)2 * n_edges;
    size_t need_lite = base_need + sizeof(int) * (size_t)n_edges;
    const bool ok_nb = (nb <= MAX_NB) && (n_nodes < (1 << 26)) && (nb >= 1);

    prep_weights<<<896, 256, 0, stream>>>(W1, W2, W3, W1t, W2t, W3t);
    mlp_kernel<<<(n_nodes + TM - 1) / TM, 256, 0, stream>>>(
        X, b1, b2, b3, W1t, W2t, W3t, out, n_nodes);

    if (ok_nb && ws_size >= need_full) {
        hipMemsetAsync(bcnt, 0, (size_t)nb * 4, stream);
        bhist_kernel<<<256, 256, 0, stream>>>(dst, bcnt, n_edges, nb);
        bscan_kernel<<<1, 256, 0, stream>>>(bcnt, boffs, bcur, nb);
        bscatter_kernel<<<(n_edges + PS_CHUNK - 1) / PS_CHUNK, 256, 0, stream>>>(
            src, dst, bcur, pairs, n_edges, nb);
        bsort_kernel<<<nb, 256, 0, stream>>>(pairs, boffs, offs, esrc,
                                             n_nodes, n_edges);
        agg_kernel<<<(n_nodes + 3) / 4, 256, 0, stream>>>(esrc, offs, out, n_nodes);
    } else if (ok_nb && ws_size >= need_lite) {
        hipMemsetAsync(bcnt, 0, (size_t)nb * 4, stream);
        bhist_kernel<<<256, 256, 0, stream>>>(dst, bcnt, n_edges, nb);
        bscan_kernel<<<1, 256, 0, stream>>>(bcnt, boffs, bcur, nb);
        bscatter_kernel<<<(n_edges + PS_CHUNK - 1) / PS_CHUNK, 256, 0, stream>>>(
            src, dst, bcur, pairs, n_edges, nb);
        bagg_kernel<<<nb, 256, 0, stream>>>(pairs, boffs, out, n_nodes);
    } else {
        zero_agg<<<3125, 256, 0, stream>>>(out, n_nodes);
        edge_agg<<<(n_edges + 7) / 8, 256, 0, stream>>>(src, dst, out, n_edges);
    }
}

// Round 3
// 583.778 us; speedup vs baseline: 4.7178x; 1.0573x over previous
//
#include <hip/hip_runtime.h>
#include <hip/hip_bf16.h>
#include <hip/hip_fp16.h>

typedef __attribute__((ext_vector_type(8))) short short8;
typedef __attribute__((ext_vector_type(4))) short short4v;
typedef __attribute__((ext_vector_type(4))) float f32x4;

#define TM 64          // nodes per block (mlp)
#define SX 136         // lds row stride (bf16) for X / H2 chunk (128 + 8 pad)
#define S1 264         // lds row stride for H1              (256 + 8 pad)

#define BK_LG 6        // 64 nodes per aggregation bucket
#define BK_N  64
#define MAX_NB 4096    // bucket-count cap (LDS histogram size)
#define PS_CHUNK 16384 // edges per bscatter block

__device__ __forceinline__ short f2bf(float x) {
    union { float f; unsigned u; } v; v.f = x;
    unsigned r = v.u + 0x7fffu + ((v.u >> 16) & 1u);
    return (short)(r >> 16);
}

// ---- weight prep: f32 [k][n] -> bf16 transposed [n][k] ----
__global__ __launch_bounds__(256) void prep_weights(
        const float* __restrict__ W1, const float* __restrict__ W2,
        const float* __restrict__ W3,
        short* __restrict__ W1t, short* __restrict__ W2t, short* __restrict__ W3t) {
    int i = blockIdx.x * 256 + threadIdx.x;
    if (i < 32768) {                       // W1: 128x256 -> W1t: 256x128
        int n = i >> 7, k = i & 127;
        W1t[i] = f2bf(W1[k * 256 + n]);
    } else if (i < 32768 + 131072) {       // W2: 256x512 -> W2t: 512x256
        int j = i - 32768;
        int n = j >> 8, k = j & 255;
        W2t[j] = f2bf(W2[k * 512 + n]);
    } else if (i < 229376) {               // W3: 512x128 -> W3t: 128x512
        int j = i - 163840;
        int n = j >> 9, k = j & 511;
        W3t[j] = f2bf(W3[k * 128 + n]);
    }
}

// ---- fused 3-layer MLP, bf16 MFMA, 64 nodes/block, 4 waves by out-col ----
// Optionally mirrors h (the 128-col MLP output) as fp16 into hh for the
// aggregation gather (halves gather bytes; fp16 keeps 11 mantissa bits).
__global__ __launch_bounds__(256) void mlp_kernel(
        const float* __restrict__ X,
        const float* __restrict__ b1f, const float* __restrict__ b2f,
        const float* __restrict__ b3f,
        const short* __restrict__ W1t, const short* __restrict__ W2t,
        const short* __restrict__ W3t,
        float* __restrict__ out, __half* __restrict__ hh, int n_nodes) {
    __shared__ short lds[TM * S1 + TM * SX];   // H1 (33792B) + X/H2chunk (17408B)
    short* ldsH1 = lds;
    short* ldsX  = lds + TM * S1;   // X aliases H2 chunk (X dead after layer1)
    short* ldsH2 = ldsX;

    const int tid  = threadIdx.x;
    const int ch   = tid >> 6;      // wave = output-column group
    const int lane = tid & 63;
    const int ln   = lane & 15;
    const int quad = lane >> 4;
    const long node0 = (long)blockIdx.x * TM;

    // ---- stage X -> LDS (f32 -> bf16): 64 rows x 32 float4 ----
    for (int i = tid; i < TM * 32; i += 256) {
        int r = i >> 5, c4 = i & 31;
        long node = node0 + r;
        float4 v = make_float4(0.f, 0.f, 0.f, 0.f);
        if (node < n_nodes) v = *(const float4*)&X[node * 128 + c4 * 4];
        short4v s;
        s.x = f2bf(v.x); s.y = f2bf(v.y); s.z = f2bf(v.z); s.w = f2bf(v.w);
        *(short4v*)&ldsX[r * SX + c4 * 4] = s;
    }
    __syncthreads();

    // ---- layer 1: H1[64x256] = relu(X @ W1 + b1); wave cols ch*64..+64 ----
#pragma unroll
    for (int nt = 0; nt < 4; ++nt) {
        int n = ch * 64 + nt * 16 + ln;
        const short* bp = &W1t[n * 128 + quad * 8];
        short8 b[4];
#pragma unroll
        for (int kk = 0; kk < 4; ++kk) b[kk] = *(const short8*)(bp + kk * 32);
        float bias = b1f[n];
#pragma unroll
        for (int m = 0; m < 4; ++m) {
            f32x4 c = {0.f, 0.f, 0.f, 0.f};
#pragma unroll
            for (int kk = 0; kk < 4; ++kk) {
                short8 a = *(const short8*)&ldsX[(m * 16 + ln) * SX + kk * 32 + quad * 8];
                c = __builtin_amdgcn_mfma_f32_16x16x32_bf16(a, b[kk], c, 0, 0, 0);
            }
#pragma unroll
            for (int rr = 0; rr < 4; ++rr) {
                float h = c[rr] + bias;
                h = h > 0.f ? h : 0.f;
                ldsH1[(m * 16 + quad * 4 + rr) * S1 + n] = f2bf(h);
            }
        }
    }
    __syncthreads();   // H1 complete; X region now free for H2 chunks

    // ---- layers 2+3 fused over 4 chunks of 128 H2 cols ----
    f32x4 acc3[4][2] = {};
#pragma unroll 1
    for (int cc = 0; cc < 4; ++cc) {
        // layer 2 part: H2[:, cc*128..+128] = relu(H1 @ W2[:,chunk] + b2)
#pragma unroll
        for (int nt = 0; nt < 2; ++nt) {
            int n2 = cc * 128 + ch * 32 + nt * 16 + ln;
            const short* bp = &W2t[n2 * 256 + quad * 8];
            short8 b[8];
#pragma unroll
            for (int kk = 0; kk < 8; ++kk) b[kk] = *(const short8*)(bp + kk * 32);
            float bias = b2f[n2];
            int nl = ch * 32 + nt * 16 + ln;   // col within chunk
#pragma unroll
            for (int m = 0; m < 4; ++m) {
                f32x4 c = {0.f, 0.f, 0.f, 0.f};
#pragma unroll
                for (int kk = 0; kk < 8; ++kk) {
                    short8 a = *(const short8*)&ldsH1[(m * 16 + ln) * S1 + kk * 32 + quad * 8];
                    c = __builtin_amdgcn_mfma_f32_16x16x32_bf16(a, b[kk], c, 0, 0, 0);
                }
#pragma unroll
                for (int rr = 0; rr < 4; ++rr) {
                    float h = c[rr] + bias;
                    h = h > 0.f ? h : 0.f;
                    ldsH2[(m * 16 + quad * 4 + rr) * SX + nl] = f2bf(h);
                }
            }
        }
        __syncthreads();   // chunk fully written

        // layer 3 part: acc3 += H2chunk @ W3[chunk rows, :]
#pragma unroll
        for (int nt = 0; nt < 2; ++nt) {
            int n3 = ch * 32 + nt * 16 + ln;
            const short* bp = &W3t[n3 * 512 + cc * 128 + quad * 8];
            short8 b[4];
#pragma unroll
            for (int kk = 0; kk < 4; ++kk) b[kk] = *(const short8*)(bp + kk * 32);
#pragma unroll
            for (int m = 0; m < 4; ++m) {
#pragma unroll
                for (int kk = 0; kk < 4; ++kk) {
                    short8 a = *(const short8*)&ldsH2[(m * 16 + ln) * SX + kk * 32 + quad * 8];
                    acc3[m][nt] = __builtin_amdgcn_mfma_f32_16x16x32_bf16(a, b[kk], acc3[m][nt], 0, 0, 0);
                }
            }
        }
        __syncthreads();   // chunk consumed; safe to overwrite next iter
    }

    // ---- epilogue: out[node][n3] = acc3 + b3 (+ fp16 mirror) ----
#pragma unroll
    for (int nt = 0; nt < 2; ++nt) {
        int n3 = ch * 32 + nt * 16 + ln;
        float bias = b3f[n3];
#pragma unroll
        for (int m = 0; m < 4; ++m) {
#pragma unroll
            for (int rr = 0; rr < 4; ++rr) {
                long node = node0 + m * 16 + quad * 4 + rr;
                if (node < n_nodes) {
                    float v = acc3[m][nt][rr] + bias;
                    out[node * 256 + n3] = v;
                    if (hh) hh[node * 128 + n3] = __float2half(v);
                }
            }
        }
    }
}

// ============ two-level CSR build: bucket scatter + in-bucket sort ============
// Buckets of 64 consecutive dst nodes. Edges packed (dstloc<<26)|src.

// ---- B1: bucket histogram with per-block LDS aggregation ----
__global__ __launch_bounds__(256) void bhist_kernel(
        const int* __restrict__ dst, int* __restrict__ bcnt,
        int n_edges, int nb) {
    __shared__ int h[MAX_NB];
    int tid = threadIdx.x;
    for (int b = tid; b < nb; b += 256) h[b] = 0;
    __syncthreads();
    for (int e = blockIdx.x * 256 + tid; e < n_edges; e += gridDim.x * 256)
        atomicAdd(&h[dst[e] >> BK_LG], 1);
    __syncthreads();
    for (int b = tid; b < nb; b += 256) {
        int c = h[b];
        if (c) atomicAdd(&bcnt[b], c);
    }
}

// ---- B2: single-block exclusive scan of bucket counts (nb <= MAX_NB) ----
__global__ __launch_bounds__(256) void bscan_kernel(
        const int* __restrict__ bcnt, int* __restrict__ boffs,
        int* __restrict__ bcur, int nb) {
    __shared__ int s[256];
    int t = threadIdx.x;
    int per = (nb + 255) >> 8;
    int lo = t * per;
    int sum = 0;
    for (int i = 0; i < per; ++i) {
        int b = lo + i;
        if (b < nb) sum += bcnt[b];
    }
    s[t] = sum;
    __syncthreads();
#pragma unroll
    for (int off = 1; off < 256; off <<= 1) {
        int v = (t >= off) ? s[t - off] : 0;
        __syncthreads();
        s[t] += v;
        __syncthreads();
    }
    int base = (t == 0) ? 0 : s[t - 1];
    for (int i = 0; i < per; ++i) {
        int b = lo + i;
        if (b < nb) {
            int c = bcnt[b];
            boffs[b] = base;
            bcur[b]  = base;
            base += c;
        }
    }
    if (t == 255) boffs[nb] = s[255];
}

// ---- B3: scatter packed edges into bucket regions ----
// Per-block LDS histogram + bulk cursor reservation -> each block writes a
// contiguous run per bucket (avg ~10 edges = 42B) instead of isolated 4B.
__global__ __launch_bounds__(256) void bscatter_kernel(
        const int* __restrict__ src, const int* __restrict__ dst,
        int* __restrict__ bcur, unsigned* __restrict__ pairs,
        int n_edges, int nb) {
    __shared__ int h[MAX_NB];
    int tid = threadIdx.x;
    long e0 = (long)blockIdx.x * PS_CHUNK;
    int cnt = n_edges - (int)e0;
    if (cnt > PS_CHUNK) cnt = PS_CHUNK;
    if (cnt <= 0) return;
    for (int b = tid; b < nb; b += 256) h[b] = 0;
    __syncthreads();
    for (int i = tid; i < cnt; i += 256)
        atomicAdd(&h[dst[e0 + i] >> BK_LG], 1);
    __syncthreads();
    for (int b = tid; b < nb; b += 256) {
        int c = h[b];
        h[b] = c ? atomicAdd(&bcur[b], c) : 0;
    }
    __syncthreads();
    for (int i = tid; i < cnt; i += 256) {
        int d = dst[e0 + i];
        int s = src[e0 + i];
        int p = atomicAdd(&h[d >> BK_LG], 1);
        pairs[p] = ((unsigned)(d & (BK_N - 1)) << 26) | (unsigned)s;
    }
}

// ---- B4: in-bucket 64-way counting sort -> full per-node CSR ----
__global__ __launch_bounds__(256) void bsort_kernel(
        const unsigned* __restrict__ pairs, const int* __restrict__ boffs,
        int* __restrict__ offs, int* __restrict__ esrc,
        int n_nodes, int n_edges) {
    __shared__ int hist[BK_N];
    __shared__ int cur[BK_N];
    const int tid = threadIdx.x;
    const int b = blockIdx.x;
    const int base = boffs[b];
    const int cnt = boffs[b + 1] - base;

    if (tid < BK_N) hist[tid] = 0;
    __syncthreads();
    for (int i = tid; i < cnt; i += 256)
        atomicAdd(&hist[pairs[base + i] >> 26], 1);
    __syncthreads();
    if (tid == 0) {
        int run = base;
#pragma unroll
        for (int k = 0; k < BK_N; ++k) { cur[k] = run; run += hist[k]; }
    }
    __syncthreads();
    if (tid < BK_N) {
        int node = (b << BK_LG) + tid;
        if (node < n_nodes) offs[node] = cur[tid];
    }
    if (b == 0 && tid == 0) offs[n_nodes] = n_edges;
    __syncthreads();   // offs written before cursors mutate
    for (int i = tid; i < cnt; i += 256) {
        unsigned p = pairs[base + i];
        int pos = atomicAdd(&cur[p >> 26], 1);
        esrc[pos] = (int)(p & 0x03FFFFFFu);
    }
}

// ---- aggregation from fp16 mirror: one wave per node, no atomics ----
__global__ __launch_bounds__(256) void agg_half_kernel(
        const int* __restrict__ esrc, const int* __restrict__ offs,
        const __half* __restrict__ hh, float* __restrict__ out, int n_nodes) {
    int node = blockIdx.x * 4 + (threadIdx.x >> 6);
    if (node >= n_nodes) return;
    const int l2 = (threadIdx.x & 63) * 2;
    const int s0 = offs[node];
    const int s1 = offs[node + 1];
    float ax = 0.f, ay = 0.f;
    int j = s0;
    for (; j + 8 <= s1; j += 8) {
        int s[8];
#pragma unroll
        for (int u = 0; u < 8; ++u) s[u] = esrc[j + u];
        __half2 v[8];
#pragma unroll
        for (int u = 0; u < 8; ++u) v[u] = *(const __half2*)&hh[(long)s[u] * 128 + l2];
#pragma unroll
        for (int u = 0; u < 8; ++u) {
            float2 f = __half22float2(v[u]);
            ax += f.x; ay += f.y;
        }
    }
    for (; j < s1; ++j) {
        float2 f = __half22float2(*(const __half2*)&hh[(long)esrc[j] * 128 + l2]);
        ax += f.x; ay += f.y;
    }
    *(float2*)&out[(long)node * 256 + 128 + l2] = make_float2(ax, ay);
}

// ---- aggregation from f32 out rows (fallback when no hh space) ----
__global__ __launch_bounds__(256) void agg_kernel(
        const int* __restrict__ esrc, const int* __restrict__ offs,
        float* __restrict__ out, int n_nodes) {
    int node = blockIdx.x * 4 + (threadIdx.x >> 6);
    if (node >= n_nodes) return;
    const int l2 = (threadIdx.x & 63) * 2;
    const int s0 = offs[node];
    const int s1 = offs[node + 1];
    float ax = 0.f, ay = 0.f;
    int j = s0;
    for (; j + 8 <= s1; j += 8) {
        int s[8];
#pragma unroll
        for (int u = 0; u < 8; ++u) s[u] = esrc[j + u];
        float2 v[8];
#pragma unroll
        for (int u = 0; u < 8; ++u) v[u] = *(const float2*)&out[(long)s[u] * 256 + l2];
#pragma unroll
        for (int u = 0; u < 8; ++u) { ax += v[u].x; ay += v[u].y; }
    }
    for (; j < s1; ++j) {
        float2 v = *(const float2*)&out[(long)esrc[j] * 256 + l2];
        ax += v.x; ay += v.y;
    }
    *(float2*)&out[(long)node * 256 + 128 + l2] = make_float2(ax, ay);
}

// ---- mid fallback: block-per-bucket LDS accumulation ----
__global__ __launch_bounds__(256) void bagg_kernel(
        const unsigned* __restrict__ pairs, const int* __restrict__ boffs,
        float* __restrict__ out, int n_nodes) {
    __shared__ float acc[BK_N * 128];
    __shared__ unsigned eb[512];
    const int tid  = threadIdx.x;
    const int col  = tid & 127;
    const int half = tid >> 7;
    const int node0 = blockIdx.x << BK_LG;

    for (int i = tid; i < BK_N * 128; i += 256) acc[i] = 0.f;

    const int s0 = boffs[blockIdx.x];
    const int s1 = boffs[blockIdx.x + 1];

    for (int j0 = s0; j0 < s1; j0 += 512) {
        int m = s1 - j0;
        if (m > 512) m = 512;
        for (int i = tid; i < m; i += 256) eb[i] = pairs[j0 + i];
        __syncthreads();
        int i = half;
        for (; i + 8 <= m; i += 8) {
            unsigned p0 = eb[i], p1 = eb[i + 2], p2 = eb[i + 4], p3 = eb[i + 6];
            float v0 = out[(long)(p0 & 0x03FFFFFFu) * 256 + col];
            float v1 = out[(long)(p1 & 0x03FFFFFFu) * 256 + col];
            float v2 = out[(long)(p2 & 0x03FFFFFFu) * 256 + col];
            float v3 = out[(long)(p3 & 0x03FFFFFFu) * 256 + col];
            atomicAdd(&acc[(p0 >> 26) * 128 + col], v0);
            atomicAdd(&acc[(p1 >> 26) * 128 + col], v1);
            atomicAdd(&acc[(p2 >> 26) * 128 + col], v2);
            atomicAdd(&acc[(p3 >> 26) * 128 + col], v3);
        }
        for (; i < m; i += 2) {
            unsigned pk = eb[i];
            float v = out[(long)(pk & 0x03FFFFFFu) * 256 + col];
            atomicAdd(&acc[(pk >> 26) * 128 + col], v);
        }
        __syncthreads();
    }

    for (int i = tid; i < BK_N * 128; i += 256) {
        int n = node0 + (i >> 7);
        if (n < n_nodes) out[(long)n * 256 + 128 + (i & 127)] = acc[i];
    }
}

// ---- last fallback (tiny ws): zero agg + atomic scatter-add ----
__global__ __launch_bounds__(256) void zero_agg(float* __restrict__ out, int n_nodes) {
    int i = blockIdx.x * 256 + threadIdx.x;
    int total = n_nodes * 32;
    for (; i < total; i += gridDim.x * 256) {
        int n = i >> 5, q = i & 31;
        *(float4*)&out[(long)n * 256 + 128 + q * 4] = make_float4(0.f, 0.f, 0.f, 0.f);
    }
}

__global__ __launch_bounds__(256) void edge_agg(
        const int* __restrict__ src, const int* __restrict__ dst,
        float* __restrict__ out, int n_edges) {
    int e = blockIdx.x * 8 + (threadIdx.x >> 5);
    if (e >= n_edges) return;
    int l = threadIdx.x & 31;
    long s = src[e];
    long d = dst[e];
    const float4 v = *(const float4*)&out[s * 256 + l * 4];
    float* p = &out[d * 256 + 128 + l * 4];
    unsafeAtomicAdd(p + 0, v.x);
    unsafeAtomicAdd(p + 1, v.y);
    unsafeAtomicAdd(p + 2, v.z);
    unsafeAtomicAdd(p + 3, v.w);
}

extern "C" void kernel_launch(void* const* d_in, const int* in_sizes, int n_in,
                              void* d_out, int out_size, void* d_ws, size_t ws_size,
                              hipStream_t stream) {
    const float* X   = (const float*)d_in[0];
    const int*   src = (const int*)d_in[1];
    const int*   dst = (const int*)d_in[2];
    const float* W1  = (const float*)d_in[3];
    const float* b1  = (const float*)d_in[4];
    const float* W2  = (const float*)d_in[5];
    const float* b2  = (const float*)d_in[6];
    const float* W3  = (const float*)d_in[7];
    const float* b3  = (const float*)d_in[8];
    float* out = (float*)d_out;

    const int n_nodes = in_sizes[0] / 128;
    const int n_edges = in_sizes[1];
    const int nb = (n_nodes + BK_N - 1) >> BK_LG;

    char* ws = (char*)d_ws;
    short* W1t = (short*)ws;              // 32768 bf16
    short* W2t = W1t + 32768;             // 131072 bf16
    short* W3t = W2t + 131072;            // 65536 bf16  (total 448 KiB used)

    int* bcnt   = (int*)(ws + 512 * 1024);        // nb
    int* boffs  = bcnt + nb;                      // nb + 1
    int* bcur   = boffs + nb + 1;                 // nb
    int* offs   = bcur + nb;                      // n_nodes + 1
    unsigned* pairs = (unsigned*)(offs + n_nodes + 1);  // n_edges
    int* esrc   = (int*)(pairs + n_edges);        // n_edges
    __half* hh  = (__half*)(esrc + n_edges);      // n_nodes*128 fp16 mirror

    size_t base_need = 512 * 1024 +
                       sizeof(int) * ((size_t)3 * nb + 1 + (size_t)n_nodes + 1);
    size_t need_full = base_need + sizeof(int) * (size_t)2 * n_edges;
    size_t need_half = need_full + (size_t)2 * 128 * n_nodes;
    size_t need_lite = base_need + sizeof(int) * (size_t)n_edges;
    const bool ok_nb = (nb <= MAX_NB) && (n_nodes < (1 << 26)) && (nb >= 1);
    const bool tier_half = ok_nb && ws_size >= need_half;
    const bool tier_full = ok_nb && ws_size >= need_full;
    const bool tier_lite = ok_nb && ws_size >= need_lite;

    prep_weights<<<896, 256, 0, stream>>>(W1, W2, W3, W1t, W2t, W3t);
    mlp_kernel<<<(n_nodes + TM - 1) / TM, 256, 0, stream>>>(
        X, b1, b2, b3, W1t, W2t, W3t, out, tier_half ? hh : (__half*)nullptr,
        n_nodes);

    if (tier_full) {
        hipMemsetAsync(bcnt, 0, (size_t)nb * 4, stream);
        bhist_kernel<<<256, 256, 0, stream>>>(dst, bcnt, n_edges, nb);
        bscan_kernel<<<1, 256, 0, stream>>>(bcnt, boffs, bcur, nb);
        bscatter_kernel<<<(n_edges + PS_CHUNK - 1) / PS_CHUNK, 256, 0, stream>>>(
            src, dst, bcur, pairs, n_edges, nb);
        bsort_kernel<<<nb, 256, 0, stream>>>(pairs, boffs, offs, esrc,
                                             n_nodes, n_edges);
        if (tier_half)
            agg_half_kernel<<<(n_nodes + 3) / 4, 256, 0, stream>>>(
                esrc, offs, hh, out, n_nodes);
        else
            agg_kernel<<<(n_nodes + 3) / 4, 256, 0, stream>>>(
                esrc, offs, out, n_nodes);
    } else if (tier_lite) {
        hipMemsetAsync(bcnt, 0, (size_t)nb * 4, stream);
        bhist_kernel<<<256, 256, 0, stream>>>(dst, bcnt, n_edges, nb);
        bscan_kernel<<<1, 256, 0, stream>>>(bcnt, boffs, bcur, nb);
        bscatter_kernel<<<(n_edges + PS_CHUNK - 1) / PS_CHUNK, 256, 0, stream>>>(
            src, dst, bcur, pairs, n_edges, nb);
        bagg_kernel<<<nb, 256, 0, stream>>>(pairs, boffs, out, n_nodes);
    } else {
        zero_agg<<<3125, 256, 0, stream>>>(out, n_nodes);
        edge_agg<<<(n_edges + 7) / 8, 256, 0, stream>>>(src, dst, out, n_edges);
    }
}

// Round 4
// 555.572 us; speedup vs baseline: 4.9574x; 1.0508x over previous
//
#include <hip/hip_runtime.h>
#include <hip/hip_bf16.h>
#include <hip/hip_fp16.h>

typedef __attribute__((ext_vector_type(8))) short short8;
typedef __attribute__((ext_vector_type(4))) short short4v;
typedef __attribute__((ext_vector_type(4))) float f32x4;

#define TM 64          // nodes per block (mlp)
#define SX 136         // lds row stride (bf16) for X / H2 chunk (128 + 8 pad)
#define S1 264         // lds row stride for H1              (256 + 8 pad)

#define BK_LG 6        // 64 nodes per aggregation bucket
#define BK_N  64
#define MAX_NB 4096    // bucket-count cap (LDS histogram size)
#define PS_CHUNK 16384 // edges per bscatter block

__device__ __forceinline__ short f2bf(float x) {
    union { float f; unsigned u; } v; v.f = x;
    unsigned r = v.u + 0x7fffu + ((v.u >> 16) & 1u);
    return (short)(r >> 16);
}

// ---- weight prep: f32 [k][n] -> bf16 transposed [n][k] ----
__global__ __launch_bounds__(256) void prep_weights(
        const float* __restrict__ W1, const float* __restrict__ W2,
        const float* __restrict__ W3,
        short* __restrict__ W1t, short* __restrict__ W2t, short* __restrict__ W3t) {
    int i = blockIdx.x * 256 + threadIdx.x;
    if (i < 32768) {                       // W1: 128x256 -> W1t: 256x128
        int n = i >> 7, k = i & 127;
        W1t[i] = f2bf(W1[k * 256 + n]);
    } else if (i < 32768 + 131072) {       // W2: 256x512 -> W2t: 512x256
        int j = i - 32768;
        int n = j >> 8, k = j & 255;
        W2t[j] = f2bf(W2[k * 512 + n]);
    } else if (i < 229376) {               // W3: 512x128 -> W3t: 128x512
        int j = i - 163840;
        int n = j >> 9, k = j & 511;
        W3t[j] = f2bf(W3[k * 128 + n]);
    }
}

// ---- fused 3-layer MLP, bf16 MFMA, 64 nodes/block, 8 waves (512 thr) ----
// 512-thread blocks keep the 51200B LDS footprint -> 3 blocks/CU but now
// 24 waves/CU (was 12) for latency hiding across the 10 barriers.
// Optionally mirrors h (the 128-col MLP output) as fp16 into hh for the
// aggregation gather (halves gather bytes; fp16 keeps 11 mantissa bits).
__global__ __launch_bounds__(512) void mlp_kernel(
        const float* __restrict__ X,
        const float* __restrict__ b1f, const float* __restrict__ b2f,
        const float* __restrict__ b3f,
        const short* __restrict__ W1t, const short* __restrict__ W2t,
        const short* __restrict__ W3t,
        float* __restrict__ out, __half* __restrict__ hh, int n_nodes) {
    __shared__ short lds[TM * S1 + TM * SX];   // H1 (33792B) + X/H2chunk (17408B)
    short* ldsH1 = lds;
    short* ldsX  = lds + TM * S1;   // X aliases H2 chunk (X dead after layer1)
    short* ldsH2 = ldsX;

    const int tid  = threadIdx.x;
    const int ch   = tid >> 6;      // wave 0..7 = output-column group
    const int lane = tid & 63;
    const int ln   = lane & 15;
    const int quad = lane >> 4;
    const long node0 = (long)blockIdx.x * TM;

    // ---- stage X -> LDS (f32 -> bf16): 64 rows x 32 float4, 4 iters ----
    for (int i = tid; i < TM * 32; i += 512) {
        int r = i >> 5, c4 = i & 31;
        long node = node0 + r;
        float4 v = make_float4(0.f, 0.f, 0.f, 0.f);
        if (node < n_nodes) v = *(const float4*)&X[node * 128 + c4 * 4];
        short4v s;
        s.x = f2bf(v.x); s.y = f2bf(v.y); s.z = f2bf(v.z); s.w = f2bf(v.w);
        *(short4v*)&ldsX[r * SX + c4 * 4] = s;
    }
    __syncthreads();

    // ---- layer 1: H1[64x256] = relu(X @ W1 + b1); wave cols ch*32..+32 ----
#pragma unroll
    for (int nt = 0; nt < 2; ++nt) {
        int n = ch * 32 + nt * 16 + ln;
        const short* bp = &W1t[n * 128 + quad * 8];
        short8 b[4];
#pragma unroll
        for (int kk = 0; kk < 4; ++kk) b[kk] = *(const short8*)(bp + kk * 32);
        float bias = b1f[n];
#pragma unroll
        for (int m = 0; m < 4; ++m) {
            f32x4 c = {0.f, 0.f, 0.f, 0.f};
#pragma unroll
            for (int kk = 0; kk < 4; ++kk) {
                short8 a = *(const short8*)&ldsX[(m * 16 + ln) * SX + kk * 32 + quad * 8];
                c = __builtin_amdgcn_mfma_f32_16x16x32_bf16(a, b[kk], c, 0, 0, 0);
            }
#pragma unroll
            for (int rr = 0; rr < 4; ++rr) {
                float h = c[rr] + bias;
                h = h > 0.f ? h : 0.f;
                ldsH1[(m * 16 + quad * 4 + rr) * S1 + n] = f2bf(h);
            }
        }
    }
    __syncthreads();   // H1 complete; X region now free for H2 chunks

    // ---- layers 2+3 fused over 4 chunks of 128 H2 cols ----
    f32x4 acc3[4] = {};
#pragma unroll 1
    for (int cc = 0; cc < 4; ++cc) {
        // layer 2 part: H2[:, cc*128..+128] = relu(H1 @ W2[:,chunk] + b2)
        {
            int n2 = cc * 128 + ch * 16 + ln;
            const short* bp = &W2t[n2 * 256 + quad * 8];
            short8 b[8];
#pragma unroll
            for (int kk = 0; kk < 8; ++kk) b[kk] = *(const short8*)(bp + kk * 32);
            float bias = b2f[n2];
            int nl = ch * 16 + ln;   // col within chunk
#pragma unroll
            for (int m = 0; m < 4; ++m) {
                f32x4 c = {0.f, 0.f, 0.f, 0.f};
#pragma unroll
                for (int kk = 0; kk < 8; ++kk) {
                    short8 a = *(const short8*)&ldsH1[(m * 16 + ln) * S1 + kk * 32 + quad * 8];
                    c = __builtin_amdgcn_mfma_f32_16x16x32_bf16(a, b[kk], c, 0, 0, 0);
                }
#pragma unroll
                for (int rr = 0; rr < 4; ++rr) {
                    float h = c[rr] + bias;
                    h = h > 0.f ? h : 0.f;
                    ldsH2[(m * 16 + quad * 4 + rr) * SX + nl] = f2bf(h);
                }
            }
        }
        __syncthreads();   // chunk fully written

        // layer 3 part: acc3 += H2chunk @ W3[chunk rows, :]
        {
            int n3 = ch * 16 + ln;
            const short* bp = &W3t[n3 * 512 + cc * 128 + quad * 8];
            short8 b[4];
#pragma unroll
            for (int kk = 0; kk < 4; ++kk) b[kk] = *(const short8*)(bp + kk * 32);
#pragma unroll
            for (int m = 0; m < 4; ++m) {
#pragma unroll
                for (int kk = 0; kk < 4; ++kk) {
                    short8 a = *(const short8*)&ldsH2[(m * 16 + ln) * SX + kk * 32 + quad * 8];
                    acc3[m] = __builtin_amdgcn_mfma_f32_16x16x32_bf16(a, b[kk], acc3[m], 0, 0, 0);
                }
            }
        }
        __syncthreads();   // chunk consumed; safe to overwrite next iter
    }

    // ---- epilogue: out[node][n3] = acc3 + b3 (+ fp16 mirror) ----
    {
        int n3 = ch * 16 + ln;
        float bias = b3f[n3];
#pragma unroll
        for (int m = 0; m < 4; ++m) {
#pragma unroll
            for (int rr = 0; rr < 4; ++rr) {
                long node = node0 + m * 16 + quad * 4 + rr;
                if (node < n_nodes) {
                    float v = acc3[m][rr] + bias;
                    out[node * 256 + n3] = v;
                    if (hh) hh[node * 128 + n3] = __float2half(v);
                }
            }
        }
    }
}

// ============ two-level CSR build: bucket scatter + in-bucket sort ============
// Buckets of 64 consecutive dst nodes. Edges packed (dstloc<<26)|src.

// ---- B1: bucket histogram with per-block LDS aggregation ----
__global__ __launch_bounds__(256) void bhist_kernel(
        const int* __restrict__ dst, int* __restrict__ bcnt,
        int n_edges, int nb) {
    __shared__ int h[MAX_NB];
    int tid = threadIdx.x;
    for (int b = tid; b < nb; b += 256) h[b] = 0;
    __syncthreads();
    for (int e = blockIdx.x * 256 + tid; e < n_edges; e += gridDim.x * 256)
        atomicAdd(&h[dst[e] >> BK_LG], 1);
    __syncthreads();
    for (int b = tid; b < nb; b += 256) {
        int c = h[b];
        if (c) atomicAdd(&bcnt[b], c);
    }
}

// ---- B2: single-block exclusive scan of bucket counts (nb <= MAX_NB) ----
__global__ __launch_bounds__(256) void bscan_kernel(
        const int* __restrict__ bcnt, int* __restrict__ boffs,
        int* __restrict__ bcur, int nb) {
    __shared__ int s[256];
    int t = threadIdx.x;
    int per = (nb + 255) >> 8;
    int lo = t * per;
    int sum = 0;
    for (int i = 0; i < per; ++i) {
        int b = lo + i;
        if (b < nb) sum += bcnt[b];
    }
    s[t] = sum;
    __syncthreads();
#pragma unroll
    for (int off = 1; off < 256; off <<= 1) {
        int v = (t >= off) ? s[t - off] : 0;
        __syncthreads();
        s[t] += v;
        __syncthreads();
    }
    int base = (t == 0) ? 0 : s[t - 1];
    for (int i = 0; i < per; ++i) {
        int b = lo + i;
        if (b < nb) {
            int c = bcnt[b];
            boffs[b] = base;
            bcur[b]  = base;
            base += c;
        }
    }
    if (t == 255) boffs[nb] = s[255];
}

// ---- B3: scatter packed edges into bucket regions ----
// Per-block LDS histogram + bulk cursor reservation -> each block writes a
// contiguous run per bucket (avg ~10 edges = 42B) instead of isolated 4B.
__global__ __launch_bounds__(256) void bscatter_kernel(
        const int* __restrict__ src, const int* __restrict__ dst,
        int* __restrict__ bcur, unsigned* __restrict__ pairs,
        int n_edges, int nb) {
    __shared__ int h[MAX_NB];
    int tid = threadIdx.x;
    long e0 = (long)blockIdx.x * PS_CHUNK;
    int cnt = n_edges - (int)e0;
    if (cnt > PS_CHUNK) cnt = PS_CHUNK;
    if (cnt <= 0) return;
    for (int b = tid; b < nb; b += 256) h[b] = 0;
    __syncthreads();
    for (int i = tid; i < cnt; i += 256)
        atomicAdd(&h[dst[e0 + i] >> BK_LG], 1);
    __syncthreads();
    for (int b = tid; b < nb; b += 256) {
        int c = h[b];
        h[b] = c ? atomicAdd(&bcur[b], c) : 0;
    }
    __syncthreads();
    for (int i = tid; i < cnt; i += 256) {
        int d = dst[e0 + i];
        int s = src[e0 + i];
        int p = atomicAdd(&h[d >> BK_LG], 1);
        pairs[p] = ((unsigned)(d & (BK_N - 1)) << 26) | (unsigned)s;
    }
}

// ---- B4: in-bucket 64-way counting sort -> full per-node CSR ----
__global__ __launch_bounds__(256) void bsort_kernel(
        const unsigned* __restrict__ pairs, const int* __restrict__ boffs,
        int* __restrict__ offs, int* __restrict__ esrc,
        int n_nodes, int n_edges) {
    __shared__ int hist[BK_N];
    __shared__ int cur[BK_N];
    const int tid = threadIdx.x;
    const int b = blockIdx.x;
    const int base = boffs[b];
    const int cnt = boffs[b + 1] - base;

    if (tid < BK_N) hist[tid] = 0;
    __syncthreads();
    for (int i = tid; i < cnt; i += 256)
        atomicAdd(&hist[pairs[base + i] >> 26], 1);
    __syncthreads();
    if (tid == 0) {
        int run = base;
#pragma unroll
        for (int k = 0; k < BK_N; ++k) { cur[k] = run; run += hist[k]; }
    }
    __syncthreads();
    if (tid < BK_N) {
        int node = (b << BK_LG) + tid;
        if (node < n_nodes) offs[node] = cur[tid];
    }
    if (b == 0 && tid == 0) offs[n_nodes] = n_edges;
    __syncthreads();   // offs written before cursors mutate
    for (int i = tid; i < cnt; i += 256) {
        unsigned p = pairs[base + i];
        int pos = atomicAdd(&cur[p >> 26], 1);
        esrc[pos] = (int)(p & 0x03FFFFFFu);
    }
}

// ---- aggregation from fp16 mirror: one wave per node, no atomics ----
__global__ __launch_bounds__(256) void agg_half_kernel(
        const int* __restrict__ esrc, const int* __restrict__ offs,
        const __half* __restrict__ hh, float* __restrict__ out, int n_nodes) {
    int node = blockIdx.x * 4 + (threadIdx.x >> 6);
    if (node >= n_nodes) return;
    const int l2 = (threadIdx.x & 63) * 2;
    const int s0 = offs[node];
    const int s1 = offs[node + 1];
    float ax = 0.f, ay = 0.f;
    int j = s0;
    for (; j + 8 <= s1; j += 8) {
        int s[8];
#pragma unroll
        for (int u = 0; u < 8; ++u) s[u] = esrc[j + u];
        __half2 v[8];
#pragma unroll
        for (int u = 0; u < 8; ++u) v[u] = *(const __half2*)&hh[(long)s[u] * 128 + l2];
#pragma unroll
        for (int u = 0; u < 8; ++u) {
            float2 f = __half22float2(v[u]);
            ax += f.x; ay += f.y;
        }
    }
    for (; j < s1; ++j) {
        float2 f = __half22float2(*(const __half2*)&hh[(long)esrc[j] * 128 + l2]);
        ax += f.x; ay += f.y;
    }
    *(float2*)&out[(long)node * 256 + 128 + l2] = make_float2(ax, ay);
}

// ---- aggregation from f32 out rows (fallback when no hh space) ----
__global__ __launch_bounds__(256) void agg_kernel(
        const int* __restrict__ esrc, const int* __restrict__ offs,
        float* __restrict__ out, int n_nodes) {
    int node = blockIdx.x * 4 + (threadIdx.x >> 6);
    if (node >= n_nodes) return;
    const int l2 = (threadIdx.x & 63) * 2;
    const int s0 = offs[node];
    const int s1 = offs[node + 1];
    float ax = 0.f, ay = 0.f;
    int j = s0;
    for (; j + 8 <= s1; j += 8) {
        int s[8];
#pragma unroll
        for (int u = 0; u < 8; ++u) s[u] = esrc[j + u];
        float2 v[8];
#pragma unroll
        for (int u = 0; u < 8; ++u) v[u] = *(const float2*)&out[(long)s[u] * 256 + l2];
#pragma unroll
        for (int u = 0; u < 8; ++u) { ax += v[u].x; ay += v[u].y; }
    }
    for (; j < s1; ++j) {
        float2 v = *(const float2*)&out[(long)esrc[j] * 256 + l2];
        ax += v.x; ay += v.y;
    }
    *(float2*)&out[(long)node * 256 + 128 + l2] = make_float2(ax, ay);
}

// ---- mid fallback: block-per-bucket LDS accumulation ----
__global__ __launch_bounds__(256) void bagg_kernel(
        const unsigned* __restrict__ pairs, const int* __restrict__ boffs,
        float* __restrict__ out, int n_nodes) {
    __shared__ float acc[BK_N * 128];
    __shared__ unsigned eb[512];
    const int tid  = threadIdx.x;
    const int col  = tid & 127;
    const int half = tid >> 7;
    const int node0 = blockIdx.x << BK_LG;

    for (int i = tid; i < BK_N * 128; i += 256) acc[i] = 0.f;

    const int s0 = boffs[blockIdx.x];
    const int s1 = boffs[blockIdx.x + 1];

    for (int j0 = s0; j0 < s1; j0 += 512) {
        int m = s1 - j0;
        if (m > 512) m = 512;
        for (int i = tid; i < m; i += 256) eb[i] = pairs[j0 + i];
        __syncthreads();
        int i = half;
        for (; i + 8 <= m; i += 8) {
            unsigned p0 = eb[i], p1 = eb[i + 2], p2 = eb[i + 4], p3 = eb[i + 6];
            float v0 = out[(long)(p0 & 0x03FFFFFFu) * 256 + col];
            float v1 = out[(long)(p1 & 0x03FFFFFFu) * 256 + col];
            float v2 = out[(long)(p2 & 0x03FFFFFFu) * 256 + col];
            float v3 = out[(long)(p3 & 0x03FFFFFFu) * 256 + col];
            atomicAdd(&acc[(p0 >> 26) * 128 + col], v0);
            atomicAdd(&acc[(p1 >> 26) * 128 + col], v1);
            atomicAdd(&acc[(p2 >> 26) * 128 + col], v2);
            atomicAdd(&acc[(p3 >> 26) * 128 + col], v3);
        }
        for (; i < m; i += 2) {
            unsigned pk = eb[i];
            float v = out[(long)(pk & 0x03FFFFFFu) * 256 + col];
            atomicAdd(&acc[(pk >> 26) * 128 + col], v);
        }
        __syncthreads();
    }

    for (int i = tid; i < BK_N * 128; i += 256) {
        int n = node0 + (i >> 7);
        if (n < n_nodes) out[(long)n * 256 + 128 + (i & 127)] = acc[i];
    }
}

// ---- last fallback (tiny ws): zero agg + atomic scatter-add ----
__global__ __launch_bounds__(256) void zero_agg(float* __restrict__ out, int n_nodes) {
    int i = blockIdx.x * 256 + threadIdx.x;
    int total = n_nodes * 32;
    for (; i < total; i += gridDim.x * 256) {
        int n = i >> 5, q = i & 31;
        *(float4*)&out[(long)n * 256 + 128 + q * 4] = make_float4(0.f, 0.f, 0.f, 0.f);
    }
}

__global__ __launch_bounds__(256) void edge_agg(
        const int* __restrict__ src, const int* __restrict__ dst,
        float* __restrict__ out, int n_edges) {
    int e = blockIdx.x * 8 + (threadIdx.x >> 5);
    if (e >= n_edges) return;
    int l = threadIdx.x & 31;
    long s = src[e];
    long d = dst[e];
    const float4 v = *(const float4*)&out[s * 256 + l * 4];
    float* p = &out[d * 256 + 128 + l * 4];
    unsafeAtomicAdd(p + 0, v.x);
    unsafeAtomicAdd(p + 1, v.y);
    unsafeAtomicAdd(p + 2, v.z);
    unsafeAtomicAdd(p + 3, v.w);
}

extern "C" void kernel_launch(void* const* d_in, const int* in_sizes, int n_in,
                              void* d_out, int out_size, void* d_ws, size_t ws_size,
                              hipStream_t stream) {
    const float* X   = (const float*)d_in[0];
    const int*   src = (const int*)d_in[1];
    const int*   dst = (const int*)d_in[2];
    const float* W1  = (const float*)d_in[3];
    const float* b1  = (const float*)d_in[4];
    const float* W2  = (const float*)d_in[5];
    const float* b2  = (const float*)d_in[6];
    const float* W3  = (const float*)d_in[7];
    const float* b3  = (const float*)d_in[8];
    float* out = (float*)d_out;

    const int n_nodes = in_sizes[0] / 128;
    const int n_edges = in_sizes[1];
    const int nb = (n_nodes + BK_N - 1) >> BK_LG;

    char* ws = (char*)d_ws;
    short* W1t = (short*)ws;              // 32768 bf16
    short* W2t = W1t + 32768;             // 131072 bf16
    short* W3t = W2t + 131072;            // 65536 bf16  (total 448 KiB used)

    int* bcnt   = (int*)(ws + 512 * 1024);        // nb
    int* boffs  = bcnt + nb;                      // nb + 1
    int* bcur   = boffs + nb + 1;                 // nb
    int* offs   = bcur + nb;                      // n_nodes + 1
    unsigned* pairs = (unsigned*)(offs + n_nodes + 1);  // n_edges
    int* esrc   = (int*)(pairs + n_edges);        // n_edges
    __half* hh  = (__half*)(esrc + n_edges);      // n_nodes*128 fp16 mirror

    size_t base_need = 512 * 1024 +
                       sizeof(int) * ((size_t)3 * nb + 1 + (size_t)n_nodes + 1);
    size_t need_full = base_need + sizeof(int) * (size_t)2 * n_edges;
    size_t need_half = need_full + (size_t)2 * 128 * n_nodes;
    size_t need_lite = base_need + sizeof(int) * (size_t)n_edges;
    const bool ok_nb = (nb <= MAX_NB) && (n_nodes < (1 << 26)) && (nb >= 1);
    const bool tier_half = ok_nb && ws_size >= need_half;
    const bool tier_full = ok_nb && ws_size >= need_full;
    const bool tier_lite = ok_nb && ws_size >= need_lite;

    prep_weights<<<896, 256, 0, stream>>>(W1, W2, W3, W1t, W2t, W3t);
    mlp_kernel<<<(n_nodes + TM - 1) / TM, 512, 0, stream>>>(
        X, b1, b2, b3, W1t, W2t, W3t, out, tier_half ? hh : (__half*)nullptr,
        n_nodes);

    if (tier_full) {
        hipMemsetAsync(bcnt, 0, (size_t)nb * 4, stream);
        bhist_kernel<<<256, 256, 0, stream>>>(dst, bcnt, n_edges, nb);
        bscan_kernel<<<1, 256, 0, stream>>>(bcnt, boffs, bcur, nb);
        bscatter_kernel<<<(n_edges + PS_CHUNK - 1) / PS_CHUNK, 256, 0, stream>>>(
            src, dst, bcur, pairs, n_edges, nb);
        bsort_kernel<<<nb, 256, 0, stream>>>(pairs, boffs, offs, esrc,
                                             n_nodes, n_edges);
        if (tier_half)
            agg_half_kernel<<<(n_nodes + 3) / 4, 256, 0, stream>>>(
                esrc, offs, hh, out, n_nodes);
        else
            agg_kernel<<<(n_nodes + 3) / 4, 256, 0, stream>>>(
                esrc, offs, out, n_nodes);
    } else if (tier_lite) {
        hipMemsetAsync(bcnt, 0, (size_t)nb * 4, stream);
        bhist_kernel<<<256, 256, 0, stream>>>(dst, bcnt, n_edges, nb);
        bscan_kernel<<<1, 256, 0, stream>>>(bcnt, boffs, bcur, nb);
        bscatter_kernel<<<(n_edges + PS_CHUNK - 1) / PS_CHUNK, 256, 0, stream>>>(
            src, dst, bcur, pairs, n_edges, nb);
        bagg_kernel<<<nb, 256, 0, stream>>>(pairs, boffs, out, n_nodes);
    } else {
        zero_agg<<<3125, 256, 0, stream>>>(out, n_nodes);
        edge_agg<<<(n_edges + 7) / 8, 256, 0, stream>>>(src, dst, out, n_edges);
    }
}